// Round 5
// baseline (4627.114 us; speedup 1.0000x reference)
//
#include <hip/hip_runtime.h>
#include <hip/hip_bf16.h>

typedef __attribute__((ext_vector_type(8))) short short8;
typedef __attribute__((ext_vector_type(4))) float f32x4;

#define B_ 64
#define S_ 1024
#define I_ 256
#define H_ 512
#define O_ 256
#define M_ (B_ * S_)   // 65536 rows everywhere
#define SC 2.8853900817779268f   // 2*log2(e), folded into U_w, W_w, cbias

// ---------- helpers ----------
__device__ __forceinline__ ushort bf16_rne(float f) {
  unsigned u = __float_as_uint(f);
  return (ushort)((u + 0x7FFFu + ((u >> 16) & 1u)) >> 16);
}
__device__ __forceinline__ float bf16_f(ushort s) {
  return __uint_as_float(((unsigned)s) << 16);
}
__device__ __forceinline__ unsigned cvt_pk_bf16(float lo, float hi) {
  unsigned r;
  asm("v_cvt_pk_bf16_f32 %0, %1, %2" : "=v"(r) : "v"(lo), "v"(hi));
  return r;
}
__device__ __forceinline__ void gll16(const void* g, void* l) {
  __builtin_amdgcn_global_load_lds((const __attribute__((address_space(1))) void*)g,
                                   (__attribute__((address_space(3))) void*)l, 16, 0, 0);
}
// tanh where the argument has already been scaled by 2*log2(e)
__device__ __forceinline__ float tanh_pre(float a) {
  a = fminf(fmaxf(a, -26.0f), 26.0f);
  float t = exp2f(a);   // v_exp_f32
#if __has_builtin(__builtin_amdgcn_rcpf)
  return (t - 1.0f) * __builtin_amdgcn_rcpf(t + 1.0f);
#else
  return (t - 1.0f) / (t + 1.0f);
#endif
}

// ---------- fp32 -> bf16 convert (with optional scale) ----------
__global__ void cvt_kern(const float* __restrict__ in, ushort* __restrict__ out, long n,
                         float scale) {
  long i = ((long)blockIdx.x * blockDim.x + threadIdx.x) * 4;
  const long stride = (long)gridDim.x * blockDim.x * 4;
  for (; i < n; i += stride) {
    const float4 v = *(const float4*)(in + i);
    ushort4 o;
    o.x = bf16_rne(v.x * scale); o.y = bf16_rne(v.y * scale);
    o.z = bf16_rne(v.z * scale); o.w = bf16_rne(v.w * scale);
    *(ushort4*)(out + i) = o;
  }
}

__global__ void biascomb_kern(const float* __restrict__ a, const float* __restrict__ b,
                              float* __restrict__ o) {
  int i = threadIdx.x;
  o[i] = (a[i] + b[i]) * SC;
}

// ---------- small fp32 GEMM: C[M,N] = A[M,K] @ B[K,N], row-major ----------
__global__ __launch_bounds__(256) void f32gemm_kern(
    const float* __restrict__ A, const float* __restrict__ Bm,
    float* __restrict__ C, int M, int N, int K)
{
  __shared__ float As[16][16];
  __shared__ float Bs[16][17];
  const int tx = threadIdx.x & 15, ty = threadIdx.x >> 4;
  const int row = blockIdx.y * 16 + ty, col = blockIdx.x * 16 + tx;
  float acc = 0.0f;
  for (int k0 = 0; k0 < K; k0 += 16) {
    As[ty][tx] = A[(size_t)row * K + k0 + tx];
    Bs[ty][tx] = Bm[(size_t)(k0 + ty) * N + col];
    __syncthreads();
    #pragma unroll
    for (int kk = 0; kk < 16; ++kk) acc += As[ty][kk] * Bs[kk][tx];
    __syncthreads();
  }
  C[(size_t)row * N + col] = acc;
}

// ---------- matvec: y = M@x + b (fp32, M [R,C] row-major) ----------
__global__ void matvec_kern(const float* __restrict__ Mw, const float* __restrict__ x,
                            const float* __restrict__ b, float* __restrict__ y, int R, int C) {
  const int i = blockIdx.x * blockDim.x + threadIdx.x;
  if (i >= R) return;
  float acc = b[i];
  for (int k = 0; k < C; ++k) acc += Mw[(size_t)i * C + k] * x[k];
  y[i] = acc;
}

// ---------- GEMM: C[M,N] = A[M,K] @ Wt[N,K]^T + bias ----------
template<bool OUT_F32>
__global__ __launch_bounds__(256) void gemm_kern(
    const ushort* __restrict__ A, const ushort* __restrict__ Wt,
    const float* __restrict__ bias, void* __restrict__ out,
    int M, int N, int K)
{
  __shared__ char smem[16384];
  const int tid = threadIdx.x;
  const int lane = tid & 63, wave = tid >> 6;
  const int wm = wave >> 1, wn = wave & 1;
  const int nt = N >> 7;
  const int bm = blockIdx.x / nt, bn = blockIdx.x % nt;
  const long m0 = (long)bm * 128, n0 = (long)bn * 128;

  f32x4 acc[4][4] = {};
  const int KT = K >> 5;
  for (int kt = 0; kt < KT; ++kt) {
    #pragma unroll
    for (int i = 0; i < 4; ++i) {
      const int c = wave * 4 + i;
      const int isB = c >> 3;
      const int cc = c & 7;
      const int kgrp = cc >> 1, rhalf = cc & 1;
      const int row = rhalf * 64 + lane;
      const ushort* src = (isB ? Wt + (n0 + row) * (long)K : A + (m0 + row) * (long)K)
                          + (long)kt * 32 + kgrp * 8;
      gll16(src, smem + isB * 8192 + kgrp * 2048 + rhalf * 1024);
    }
    __syncthreads();
    const char* Ab = smem + (lane >> 4) * 2048;
    const char* Bb = smem + 8192 + (lane >> 4) * 2048;
    short8 af[4], bf[4];
    #pragma unroll
    for (int i = 0; i < 4; ++i) {
      af[i] = *(const short8*)(Ab + (wm * 64 + i * 16 + (lane & 15)) * 16);
      bf[i] = *(const short8*)(Bb + (wn * 64 + i * 16 + (lane & 15)) * 16);
    }
    #pragma unroll
    for (int mi = 0; mi < 4; ++mi)
      #pragma unroll
      for (int ni = 0; ni < 4; ++ni)
        acc[mi][ni] = __builtin_amdgcn_mfma_f32_16x16x32_bf16(af[mi], bf[ni], acc[mi][ni], 0, 0, 0);
    __syncthreads();
  }
  #pragma unroll
  for (int ni = 0; ni < 4; ++ni) {
    const long n = n0 + wn * 64 + ni * 16 + (lane & 15);
    const float bv = bias[n];
    #pragma unroll
    for (int mi = 0; mi < 4; ++mi) {
      const long mrow = m0 + wm * 64 + mi * 16 + (lane >> 4) * 4;
      #pragma unroll
      for (int r = 0; r < 4; ++r) {
        const float v = acc[mi][ni][r] + bv;
        if (OUT_F32) ((float*)out)[(mrow + r) * (long)N + n] = v;
        else         ((ushort*)out)[(mrow + r) * (long)N + n] = bf16_rne(v);
      }
    }
  }
}

// ---------- recurrence: h_t = tanh(xu_t + W h_{t-1}) (args pre-scaled by SC) ----------
// Round-2 structure: 4 WGs x 16 batches, 512 threads = 8 waves (2/SIMD), 4 m-tiles/wave.
// W k-slices 0..11 pinned live via asm (compiler places across unified v/a file),
// slices 12..15 in LDS (128KB). h ping-pong [2][16 rows][512 feat] bf16 (32KB),
// full-b XOR swizzle (swz = b<<4) -> 2-way max on all LDS ops. 1 barrier/step.
// Hst global store moved AFTER the barrier (vmcnt drain overlaps next step).
__global__ __launch_bounds__(512, 2) void rec_kern(
    const ushort* __restrict__ XU,   // [B*S, H] bf16, scaled; row = b*S + t
    const ushort* __restrict__ Wb,   // [H, H] bf16 row-major, scaled
    ushort* __restrict__ Hst)        // [B*S, H] bf16 (unscaled h)
{
  extern __shared__ char smem[];     // [0,32K): h pingpong   [32K,160K): W slices 12..15
  const int tid = threadIdx.x;
  const int lane = tid & 63;
  const int wave = tid >> 6;         // 0..7
  const int b = lane & 15;
  const int hi = lane >> 4;          // 0..3
  const int bg = blockIdx.x << 4;
  const int swz = b << 4;            // full-b swizzle (bit7 splits b>=8 from b<8)

  // stage W slices 12..15 -> LDS [(s-12)][mtg][1024B]
  #pragma unroll
  for (int i = 0; i < 16; ++i) {
    const int ch = wave * 16 + i;          // 0..127
    const int s = 12 + (ch >> 5);
    const int mt = ch & 31;
    const ushort* src = Wb + (size_t)(mt * 16 + b) * H_ + s * 32 + hi * 8;
    gll16(src, smem + 32768 + (size_t)(s - 12) * 32768 + mt * 1024);
  }
  // zero h ping-pong (32KB)
  {
    f32x4 zz = 0.0f;
    *(f32x4*)(smem + tid * 64) = zz;
    *(f32x4*)(smem + tid * 64 + 16) = zz;
    *(f32x4*)(smem + tid * 64 + 32) = zz;
    *(f32x4*)(smem + tid * 64 + 48) = zz;
  }
  // W registers: slices 0..11 for this wave's 4 m-tiles, pinned live via asm
  short8 wreg[4][12];
  #pragma unroll
  for (int mt = 0; mt < 4; ++mt) {
    const int mtg = wave * 4 + mt;
    const ushort* wrow = Wb + (size_t)(mtg * 16 + b) * H_ + hi * 8;
    #pragma unroll
    for (int s = 0; s < 12; ++s)
      wreg[mt][s] = *(const short8*)(wrow + s * 32);
  }
  #pragma unroll
  for (int mt = 0; mt < 4; ++mt)
    #pragma unroll
    for (int s = 0; s < 12; ++s)
      asm volatile("" : "+v"(wreg[mt][s]));
  __syncthreads();

  const ushort* xup = XU + (size_t)(bg + b) * S_ * H_ + wave * 64 + hi * 4;
  ushort* hgp = Hst + (size_t)(bg + b) * S_ * H_ + wave * 64 + hi * 4;
  const int hoff = b * 1024;                     // h row base
  const int woff = wave * 128 + hi * 8;          // epilogue LDS write base (bytes, pre-XOR)

  for (int t = 0; t < S_; ++t) {
    // issue xu loads now; consumed in the epilogue (~2k cycles later)
    uint2 xu[4];
    #pragma unroll
    for (int mt = 0; mt < 4; ++mt)
      xu[mt] = *(const uint2*)(xup + mt * 16);
    xup += H_;

    const char* hb = smem + (t & 1) * 16384 + hoff;    // h_{t-1}
    f32x4 acc[4] = {};
    __builtin_amdgcn_s_setprio(1);
    #pragma unroll
    for (int s = 0; s < 16; ++s) {
      const short8 bfrag = *(const short8*)(hb + ((s * 64 + hi * 16) ^ swz));
      #pragma unroll
      for (int mt = 0; mt < 4; ++mt) {
        short8 w;
        if (s < 12) w = wreg[mt][s];
        else w = *(const short8*)(smem + 32768 + (s - 12) * 32768 + (wave * 4 + mt) * 1024 + lane * 16);
        acc[mt] = __builtin_amdgcn_mfma_f32_16x16x32_bf16(w, bfrag, acc[mt], 0, 0, 0);
      }
    }
    __builtin_amdgcn_s_setprio(0);

    // epilogue: h_t = tanh(acc + xu) (pre-scaled arg), pack, LDS write (pre-barrier)
    char* hw = smem + ((t + 1) & 1) * 16384 + hoff;
    uint2 hv[4];
    #pragma unroll
    for (int mt = 0; mt < 4; ++mt) {
      float h0 = tanh_pre(acc[mt][0] + bf16_f((ushort)(xu[mt].x & 0xFFFFu)));
      float h1 = tanh_pre(acc[mt][1] + bf16_f((ushort)(xu[mt].x >> 16)));
      float h2 = tanh_pre(acc[mt][2] + bf16_f((ushort)(xu[mt].y & 0xFFFFu)));
      float h3 = tanh_pre(acc[mt][3] + bf16_f((ushort)(xu[mt].y >> 16)));
      hv[mt].x = cvt_pk_bf16(h0, h1);
      hv[mt].y = cvt_pk_bf16(h2, h3);
      *(uint2*)(hw + ((woff + mt * 32) ^ swz)) = hv[mt];   // next step's h
    }
    __syncthreads();  // h_t visible (and h_{t-1} reads done) before next step

    // global store after the barrier: drains at the NEXT barrier, off critical path
    #pragma unroll
    for (int mt = 0; mt < 4; ++mt)
      *(uint2*)(hgp + mt * 16) = hv[mt];
    hgp += H_;
  }
}

// ---------- launcher ----------
extern "C" void kernel_launch(void* const* d_in, const int* in_sizes, int n_in,
                              void* d_out, int out_size, void* d_ws, size_t ws_size,
                              hipStream_t stream) {
  const float* x     = (const float*)d_in[0];
  const float* U_w   = (const float*)d_in[1];
  const float* U_b   = (const float*)d_in[2];
  const float* W_w   = (const float*)d_in[3];
  const float* W_b   = (const float*)d_in[4];
  const float* V_w   = (const float*)d_in[5];
  const float* V_b   = (const float*)d_in[6];
  const float* fc1_w = (const float*)d_in[7];
  const float* fc1_b = (const float*)d_in[8];
  const float* fc2_w = (const float*)d_in[9];
  const float* fc2_b = (const float*)d_in[10];
  const float* fc3_w = (const float*)d_in[11];
  const float* fc3_b = (const float*)d_in[12];

  char* ws = (char*)d_ws;
  ushort* Hst  = (ushort*)ws;                               // 67,108,864 B
  ushort* xb16 = (ushort*)(ws + 67108864);                  // 33,554,432 B
  char*   wb   = ws + 134217728;
  ushort* U_wb = (ushort*)wb;                    // 512*256 (scaled)
  ushort* W_wb = U_wb + 131072;                  // 512*512 (scaled)
  ushort* Wcb  = W_wb + 262144;                  // 256*512
  float*  C1   = (float*)(Wcb + 131072);         // 512*512 f32
  float*  C2   = C1 + 262144;                    // 512*512 f32
  float*  Wcf  = C2 + 262144;                    // 256*512 f32
  float*  cbias = Wcf + 131072;                  // 512 f32 (scaled)
  float*  t1   = cbias + 512;
  float*  t2   = t1 + 512;
  float*  bc   = t2 + 512;
  ushort* bufA = (ushort*)d_out;                 // XU scratch (bf16), finally fp32 out

  // bf16 staging converts (U_w, W_w, cbias pre-scaled by 2*log2e)
  cvt_kern<<<2048, 256, 0, stream>>>(x, xb16, (long)M_ * I_, 1.0f);
  cvt_kern<<<128, 256, 0, stream>>>(U_w, U_wb, (long)H_ * I_, SC);
  cvt_kern<<<256, 256, 0, stream>>>(W_w, W_wb, (long)H_ * H_, SC);
  biascomb_kern<<<1, 512, 0, stream>>>(U_b, W_b, cbias);

  // fused head weights (fp32): Wc = fc3@fc2@fc1@V, bc = bias chain
  f32gemm_kern<<<dim3(32, 32), 256, 0, stream>>>(fc1_w, V_w, C1, H_, H_, H_);
  f32gemm_kern<<<dim3(32, 32), 256, 0, stream>>>(fc2_w, C1, C2, H_, H_, H_);
  f32gemm_kern<<<dim3(32, 16), 256, 0, stream>>>(fc3_w, C2, Wcf, O_, H_, H_);
  matvec_kern<<<2, 256, 0, stream>>>(fc1_w, V_b, fc1_b, t1, H_, H_);
  matvec_kern<<<2, 256, 0, stream>>>(fc2_w, t1, fc2_b, t2, H_, H_);
  matvec_kern<<<1, 256, 0, stream>>>(fc3_w, t2, fc3_b, bc, O_, H_);
  cvt_kern<<<128, 256, 0, stream>>>(Wcf, Wcb, (long)O_ * H_, 1.0f);

  // XU = x @ (SC*U^T) + SC*(U_b + W_b)   -> bufA
  gemm_kern<false><<<dim3(512 * 4), 256, 0, stream>>>(xb16, U_wb, cbias, bufA, M_, H_, I_);

  // recurrence -> Hst
  hipFuncSetAttribute((const void*)rec_kern, hipFuncAttributeMaxDynamicSharedMemorySize, 163840);
  rec_kern<<<dim3(4), dim3(512), 163840, stream>>>(bufA, W_wb, Hst);

  // head: out = Hst @ Wc^T + bc -> d_out fp32 [B,S,O]
  gemm_kern<true><<<dim3(512 * 2), 256, 0, stream>>>(Hst, Wcb, bc, d_out, M_, O_, H_);

  (void)in_sizes; (void)n_in; (void)out_size; (void)ws_size;
}

// Round 6
// 3499.885 us; speedup vs baseline: 1.3221x; 1.3221x over previous
//
#include <hip/hip_runtime.h>
#include <hip/hip_bf16.h>

typedef __attribute__((ext_vector_type(8))) short short8;
typedef __attribute__((ext_vector_type(4))) float f32x4;

#define B_ 64
#define S_ 1024
#define I_ 256
#define H_ 512
#define O_ 256
#define M_ (B_ * S_)   // 65536 rows everywhere

// ---------- helpers ----------
__device__ __forceinline__ ushort bf16_rne(float f) {
  unsigned u = __float_as_uint(f);
  return (ushort)((u + 0x7FFFu + ((u >> 16) & 1u)) >> 16);
}
__device__ __forceinline__ float bf16_f(ushort s) {
  return __uint_as_float(((unsigned)s) << 16);
}
__device__ __forceinline__ void gll16(const void* g, void* l) {
  __builtin_amdgcn_global_load_lds((const __attribute__((address_space(1))) void*)g,
                                   (__attribute__((address_space(3))) void*)l, 16, 0, 0);
}
__device__ __forceinline__ float tanh_fast(float a) {
  a = fminf(fmaxf(a, -9.0f), 9.0f);
  float t = exp2f(a * 2.8853900817779268f); // e^(2a)
#if __has_builtin(__builtin_amdgcn_rcpf)
  return (t - 1.0f) * __builtin_amdgcn_rcpf(t + 1.0f);
#else
  return (t - 1.0f) / (t + 1.0f);
#endif
}

// ---------- fp32 -> bf16 convert ----------
__global__ void cvt_kern(const float* __restrict__ in, ushort* __restrict__ out, long n) {
  long i = ((long)blockIdx.x * blockDim.x + threadIdx.x) * 4;
  const long stride = (long)gridDim.x * blockDim.x * 4;
  for (; i < n; i += stride) {
    const float4 v = *(const float4*)(in + i);
    ushort4 o;
    o.x = bf16_rne(v.x); o.y = bf16_rne(v.y); o.z = bf16_rne(v.z); o.w = bf16_rne(v.w);
    *(ushort4*)(out + i) = o;
  }
}

__global__ void biascomb_kern(const float* __restrict__ a, const float* __restrict__ b,
                              float* __restrict__ o) {
  int i = threadIdx.x;
  o[i] = a[i] + b[i];
}

// ---------- small fp32 GEMM: C[M,N] = A[M,K] @ B[K,N], row-major ----------
__global__ __launch_bounds__(256) void f32gemm_kern(
    const float* __restrict__ A, const float* __restrict__ Bm,
    float* __restrict__ C, int M, int N, int K)
{
  __shared__ float As[16][16];
  __shared__ float Bs[16][17];
  const int tx = threadIdx.x & 15, ty = threadIdx.x >> 4;
  const int row = blockIdx.y * 16 + ty, col = blockIdx.x * 16 + tx;
  float acc = 0.0f;
  for (int k0 = 0; k0 < K; k0 += 16) {
    As[ty][tx] = A[(size_t)row * K + k0 + tx];
    Bs[ty][tx] = Bm[(size_t)(k0 + ty) * N + col];
    __syncthreads();
    #pragma unroll
    for (int kk = 0; kk < 16; ++kk) acc += As[ty][kk] * Bs[kk][tx];
    __syncthreads();
  }
  C[(size_t)row * N + col] = acc;
}

// ---------- matvec: y = M@x + b (fp32, M [R,C] row-major) ----------
__global__ void matvec_kern(const float* __restrict__ Mw, const float* __restrict__ x,
                            const float* __restrict__ b, float* __restrict__ y, int R, int C) {
  const int i = blockIdx.x * blockDim.x + threadIdx.x;
  if (i >= R) return;
  float acc = b[i];
  for (int k = 0; k < C; ++k) acc += Mw[(size_t)i * C + k] * x[k];
  y[i] = acc;
}

// ---------- GEMM: C[M,N] = A[M,K] @ Wt[N,K]^T + bias ----------
template<bool OUT_F32>
__global__ __launch_bounds__(256) void gemm_kern(
    const ushort* __restrict__ A, const ushort* __restrict__ Wt,
    const float* __restrict__ bias, void* __restrict__ out,
    int M, int N, int K)
{
  __shared__ char smem[16384];
  const int tid = threadIdx.x;
  const int lane = tid & 63, wave = tid >> 6;
  const int wm = wave >> 1, wn = wave & 1;
  const int nt = N >> 7;
  const int bm = blockIdx.x / nt, bn = blockIdx.x % nt;
  const long m0 = (long)bm * 128, n0 = (long)bn * 128;

  f32x4 acc[4][4] = {};
  const int KT = K >> 5;
  for (int kt = 0; kt < KT; ++kt) {
    #pragma unroll
    for (int i = 0; i < 4; ++i) {
      const int c = wave * 4 + i;
      const int isB = c >> 3;
      const int cc = c & 7;
      const int kgrp = cc >> 1, rhalf = cc & 1;
      const int row = rhalf * 64 + lane;
      const ushort* src = (isB ? Wt + (n0 + row) * (long)K : A + (m0 + row) * (long)K)
                          + (long)kt * 32 + kgrp * 8;
      gll16(src, smem + isB * 8192 + kgrp * 2048 + rhalf * 1024);
    }
    __syncthreads();
    const char* Ab = smem + (lane >> 4) * 2048;
    const char* Bb = smem + 8192 + (lane >> 4) * 2048;
    short8 af[4], bf[4];
    #pragma unroll
    for (int i = 0; i < 4; ++i) {
      af[i] = *(const short8*)(Ab + (wm * 64 + i * 16 + (lane & 15)) * 16);
      bf[i] = *(const short8*)(Bb + (wn * 64 + i * 16 + (lane & 15)) * 16);
    }
    #pragma unroll
    for (int mi = 0; mi < 4; ++mi)
      #pragma unroll
      for (int ni = 0; ni < 4; ++ni)
        acc[mi][ni] = __builtin_amdgcn_mfma_f32_16x16x32_bf16(af[mi], bf[ni], acc[mi][ni], 0, 0, 0);
    __syncthreads();
  }
  #pragma unroll
  for (int ni = 0; ni < 4; ++ni) {
    const long n = n0 + wn * 64 + ni * 16 + (lane & 15);
    const float bv = bias[n];
    #pragma unroll
    for (int mi = 0; mi < 4; ++mi) {
      const long mrow = m0 + wm * 64 + mi * 16 + (lane >> 4) * 4;
      #pragma unroll
      for (int r = 0; r < 4; ++r) {
        const float v = acc[mi][ni][r] + bv;
        if (OUT_F32) ((float*)out)[(mrow + r) * (long)N + n] = v;
        else         ((ushort*)out)[(mrow + r) * (long)N + n] = bf16_rne(v);
      }
    }
  }
}

// ---------- recurrence: h_t = tanh(xu_t + W h_{t-1}) ----------
// EXACT round-2 structure (measured 2466us): 4 WGs x 16 batches, 512 threads =
// 8 waves (2/SIMD), 4 m-tiles/wave. W k-slices 0..11 pinned via asm, 12..15 in
// LDS (128KB). h ping-pong [2][16][512] bf16 (32KB); 1 barrier/step; stores in
// epilogue BEFORE the barrier.
// SINGLE DELTA vs round 2: swz = b<<4 (was (b&7)<<4) -> conflicts 2.62M->~530K
// (mechanism counter-validated in round 5; correctness validated there too).
__global__ __launch_bounds__(512, 2) void rec_kern(
    const ushort* __restrict__ XU,   // [B*S, H] bf16, row = b*S + t  (U_b+W_b folded in)
    const ushort* __restrict__ Wb,   // [H, H] bf16 row-major
    ushort* __restrict__ Hst)        // [B*S, H] bf16
{
  extern __shared__ char smem[];     // [0,32K): h pingpong   [32K, 160K): W slices 12..15
  const int tid = threadIdx.x;
  const int lane = tid & 63;
  const int wave = tid >> 6;         // 0..7
  const int b = lane & 15;
  const int hi = lane >> 4;          // 0..3
  const int bg = blockIdx.x << 4;
  const int swz = b << 4;            // ONLY delta vs round 2

  // stage W slices 12..15 -> LDS fragments [(s-12)][mtg][lane*16]
  #pragma unroll
  for (int i = 0; i < 16; ++i) {
    const int ch = wave * 16 + i;          // 0..127
    const int s = 12 + (ch >> 5);
    const int mt = ch & 31;
    const ushort* src = Wb + (size_t)(mt * 16 + b) * H_ + s * 32 + hi * 8;
    gll16(src, smem + 32768 + (size_t)(s - 12) * 32768 + mt * 1024);
  }
  // zero both h buffers (h_{-1} = 0 in buf 0)
  {
    f32x4 zz = 0.0f;
    *(f32x4*)(smem + tid * 64) = zz;
    *(f32x4*)(smem + tid * 64 + 16) = zz;
    *(f32x4*)(smem + tid * 64 + 32) = zz;
    *(f32x4*)(smem + tid * 64 + 48) = zz;
  }
  // W registers: slices 0..11 for this wave's 4 m-tiles, pinned live via asm
  short8 wreg[4][12];
  #pragma unroll
  for (int mt = 0; mt < 4; ++mt) {
    const int mtg = wave * 4 + mt;
    const ushort* wrow = Wb + (size_t)(mtg * 16 + b) * H_ + hi * 8;
    #pragma unroll
    for (int s = 0; s < 12; ++s)
      wreg[mt][s] = *(const short8*)(wrow + s * 32);
  }
  #pragma unroll
  for (int mt = 0; mt < 4; ++mt)
    #pragma unroll
    for (int s = 0; s < 12; ++s)
      asm volatile("" : "+v"(wreg[mt][s]));
  __syncthreads();

  const ushort* xup = XU + (size_t)(bg + b) * S_ * H_ + wave * 64 + hi * 4;
  ushort* hgp = Hst + (size_t)(bg + b) * S_ * H_ + wave * 64 + hi * 4;
  const int hoff = b * 1024;                     // within h buffer
  const int woff = (wave * 128 + hi * 8);        // epilogue LDS write base (bytes, pre-XOR)

  for (int t = 0; t < S_; ++t) {
    // issue xu loads now; consumed in the epilogue (~2k cycles later)
    uint2 xu[4];
    #pragma unroll
    for (int mt = 0; mt < 4; ++mt)
      xu[mt] = *(const uint2*)(xup + mt * 16);
    xup += H_;

    const char* hb = smem + (t & 1) * 16384 + hoff;    // h_{t-1}
    f32x4 acc[4] = {};
    #pragma unroll
    for (int s = 0; s < 16; ++s) {
      const short8 bfrag = *(const short8*)(hb + ((s * 64 + hi * 16) ^ swz));
      #pragma unroll
      for (int mt = 0; mt < 4; ++mt) {
        short8 w;
        if (s < 12) w = wreg[mt][s];
        else w = *(const short8*)(smem + 32768 + (s - 12) * 32768 + (wave * 4 + mt) * 1024 + lane * 16);
        acc[mt] = __builtin_amdgcn_mfma_f32_16x16x32_bf16(w, bfrag, acc[mt], 0, 0, 0);
      }
    }
    // epilogue: h_t = tanh(acc + xu); write to other h buffer + global
    char* hw = smem + ((t + 1) & 1) * 16384 + hoff;
    #pragma unroll
    for (int mt = 0; mt < 4; ++mt) {
      ushort4 hp;
      #pragma unroll
      for (int r = 0; r < 4; ++r) {
        const ushort xb = ((const ushort*)&xu[mt])[r];
        const float a = acc[mt][r] + bf16_f(xb);
        ((ushort*)&hp)[r] = bf16_rne(tanh_fast(a));
      }
      *(uint2*)(hw + ((woff + mt * 32) ^ swz)) = *(uint2*)&hp;   // h for next step
      *(uint2*)(hgp + mt * 16) = *(uint2*)&hp;                   // h for head GEMM
    }
    hgp += H_;
    __syncthreads();  // h_t visible (and h_{t-1} reads done) before next step
  }
}

// ---------- launcher ----------
extern "C" void kernel_launch(void* const* d_in, const int* in_sizes, int n_in,
                              void* d_out, int out_size, void* d_ws, size_t ws_size,
                              hipStream_t stream) {
  const float* x     = (const float*)d_in[0];
  const float* U_w   = (const float*)d_in[1];
  const float* U_b   = (const float*)d_in[2];
  const float* W_w   = (const float*)d_in[3];
  const float* W_b   = (const float*)d_in[4];
  const float* V_w   = (const float*)d_in[5];
  const float* V_b   = (const float*)d_in[6];
  const float* fc1_w = (const float*)d_in[7];
  const float* fc1_b = (const float*)d_in[8];
  const float* fc2_w = (const float*)d_in[9];
  const float* fc2_b = (const float*)d_in[10];
  const float* fc3_w = (const float*)d_in[11];
  const float* fc3_b = (const float*)d_in[12];

  char* ws = (char*)d_ws;
  // ws layout: [0,64M): Hst   [64M,96M): x_bf16   [128M, +~4M): weights/scratch
  ushort* Hst  = (ushort*)ws;                               // 67,108,864 B
  ushort* xb16 = (ushort*)(ws + 67108864);                  // 33,554,432 B
  char*   wb   = ws + 134217728;
  ushort* U_wb = (ushort*)wb;                    // 512*256  = 131072 elems (256KB)
  ushort* W_wb = U_wb + 131072;                  // 512*512  = 262144 (512KB)
  ushort* Wcb  = W_wb + 262144;                  // 256*512  = 131072 (256KB)
  float*  C1   = (float*)(Wcb + 131072);         // 512*512 f32 (1MB)
  float*  C2   = C1 + 262144;                    // 512*512 f32 (1MB)
  float*  Wcf  = C2 + 262144;                    // 256*512 f32 (512KB)
  float*  cbias = Wcf + 131072;                  // 512 f32
  float*  t1   = cbias + 512;                    // 512 f32
  float*  t2   = t1 + 512;                       // 512 f32
  float*  bc   = t2 + 512;                       // 256 f32
  ushort* bufA = (ushort*)d_out;                 // XU scratch (bf16), then fp32 out

  // bf16 staging converts
  cvt_kern<<<2048, 256, 0, stream>>>(x, xb16, (long)M_ * I_);
  cvt_kern<<<128, 256, 0, stream>>>(U_w, U_wb, (long)H_ * I_);
  cvt_kern<<<256, 256, 0, stream>>>(W_w, W_wb, (long)H_ * H_);
  biascomb_kern<<<1, 512, 0, stream>>>(U_b, W_b, cbias);

  // fused head weights (fp32): C1 = fc1@V, C2 = fc2@C1, Wc = fc3@C2
  f32gemm_kern<<<dim3(32, 32), 256, 0, stream>>>(fc1_w, V_w, C1, H_, H_, H_);
  f32gemm_kern<<<dim3(32, 32), 256, 0, stream>>>(fc2_w, C1, C2, H_, H_, H_);
  f32gemm_kern<<<dim3(32, 16), 256, 0, stream>>>(fc3_w, C2, Wcf, O_, H_, H_);
  // bias chain: bc = fc3@(fc2@(fc1@V_b + b1) + b2) + b3
  matvec_kern<<<2, 256, 0, stream>>>(fc1_w, V_b, fc1_b, t1, H_, H_);
  matvec_kern<<<2, 256, 0, stream>>>(fc2_w, t1, fc2_b, t2, H_, H_);
  matvec_kern<<<1, 256, 0, stream>>>(fc3_w, t2, fc3_b, bc, O_, H_);
  cvt_kern<<<128, 256, 0, stream>>>(Wcf, Wcb, (long)O_ * H_);

  // G0: XU = x @ U^T + (U_b + W_b)   -> bufA (d_out as bf16 scratch)
  gemm_kern<false><<<dim3(512 * 4), 256, 0, stream>>>(xb16, U_wb, cbias, bufA, M_, H_, I_);

  // recurrence -> Hst
  hipFuncSetAttribute((const void*)rec_kern, hipFuncAttributeMaxDynamicSharedMemorySize, 163840);
  rec_kern<<<dim3(4), dim3(512), 163840, stream>>>(bufA, W_wb, Hst);

  // head: out = Hst @ Wc^T + bc -> d_out fp32 [B,S,O]
  gemm_kern<true><<<dim3(512 * 2), 256, 0, stream>>>(Hst, Wcb, bc, d_out, M_, O_, H_);

  (void)in_sizes; (void)n_in; (void)out_size; (void)ws_size;
}

// Round 7
// 2503.124 us; speedup vs baseline: 1.8485x; 1.3982x over previous
//
#include <hip/hip_runtime.h>
#include <hip/hip_bf16.h>

typedef __attribute__((ext_vector_type(8))) short short8;
typedef __attribute__((ext_vector_type(4))) float f32x4;

#define B_ 64
#define S_ 1024
#define I_ 256
#define H_ 512
#define O_ 256
#define M_ (B_ * S_)   // 65536 rows everywhere
#define SC 2.8853900817779268f   // 2*log2(e), folded into U_w, W_w, cbias

// ---------- helpers ----------
__device__ __forceinline__ ushort bf16_rne(float f) {
  unsigned u = __float_as_uint(f);
  return (ushort)((u + 0x7FFFu + ((u >> 16) & 1u)) >> 16);
}
__device__ __forceinline__ float bf16_f(ushort s) {
  return __uint_as_float(((unsigned)s) << 16);
}
__device__ __forceinline__ unsigned cvt_pk_bf16(float lo, float hi) {
  unsigned r;
  asm("v_cvt_pk_bf16_f32 %0, %1, %2" : "=v"(r) : "v"(lo), "v"(hi));
  return r;
}
__device__ __forceinline__ void gll16(const void* g, void* l) {
  __builtin_amdgcn_global_load_lds((const __attribute__((address_space(1))) void*)g,
                                   (__attribute__((address_space(3))) void*)l, 16, 0, 0);
}
// tanh(a/SC) where the argument has already been scaled by SC = 2*log2(e):
// t = 2^a = e^(2*orig); tanh = (t-1)/(t+1). Lower clamp unnecessary:
// a << 0 -> t -> 0 -> result -1 exactly. Upper clamp guards t=inf.
__device__ __forceinline__ float tanh_pre(float a) {
#if __has_builtin(__builtin_amdgcn_exp2f)
  float t = __builtin_amdgcn_exp2f(fminf(a, 26.0f));
#else
  float t = exp2f(fminf(a, 26.0f));
#endif
#if __has_builtin(__builtin_amdgcn_rcpf)
  return (t - 1.0f) * __builtin_amdgcn_rcpf(t + 1.0f);
#else
  return (t - 1.0f) / (t + 1.0f);
#endif
}

// ---------- fp32 -> bf16 convert (with scale) ----------
__global__ void cvt_kern(const float* __restrict__ in, ushort* __restrict__ out, long n,
                         float scale) {
  long i = ((long)blockIdx.x * blockDim.x + threadIdx.x) * 4;
  const long stride = (long)gridDim.x * blockDim.x * 4;
  for (; i < n; i += stride) {
    const float4 v = *(const float4*)(in + i);
    ushort4 o;
    o.x = bf16_rne(v.x * scale); o.y = bf16_rne(v.y * scale);
    o.z = bf16_rne(v.z * scale); o.w = bf16_rne(v.w * scale);
    *(ushort4*)(out + i) = o;
  }
}

__global__ void biascomb_kern(const float* __restrict__ a, const float* __restrict__ b,
                              float* __restrict__ o) {
  int i = threadIdx.x;
  o[i] = (a[i] + b[i]) * SC;
}

// ---------- small fp32 GEMM: C[M,N] = A[M,K] @ B[K,N], row-major ----------
__global__ __launch_bounds__(256) void f32gemm_kern(
    const float* __restrict__ A, const float* __restrict__ Bm,
    float* __restrict__ C, int M, int N, int K)
{
  __shared__ float As[16][16];
  __shared__ float Bs[16][17];
  const int tx = threadIdx.x & 15, ty = threadIdx.x >> 4;
  const int row = blockIdx.y * 16 + ty, col = blockIdx.x * 16 + tx;
  float acc = 0.0f;
  for (int k0 = 0; k0 < K; k0 += 16) {
    As[ty][tx] = A[(size_t)row * K + k0 + tx];
    Bs[ty][tx] = Bm[(size_t)(k0 + ty) * N + col];
    __syncthreads();
    #pragma unroll
    for (int kk = 0; kk < 16; ++kk) acc += As[ty][kk] * Bs[kk][tx];
    __syncthreads();
  }
  C[(size_t)row * N + col] = acc;
}

// ---------- matvec: y = M@x + b (fp32), one wave per row, shuffle reduce ----------
__global__ void matvec_kern(const float* __restrict__ Mw, const float* __restrict__ x,
                            const float* __restrict__ b, float* __restrict__ y, int R, int C) {
  const int wid = (int)((blockIdx.x * blockDim.x + threadIdx.x) >> 6);
  const int lane = threadIdx.x & 63;
  if (wid >= R) return;
  float acc = 0.0f;
  for (int k = lane; k < C; k += 64) acc += Mw[(size_t)wid * C + k] * x[k];
  #pragma unroll
  for (int off = 32; off; off >>= 1) acc += __shfl_down(acc, off, 64);
  if (lane == 0) y[wid] = acc + b[wid];
}

// ---------- GEMM: C[M,N] = A[M,K] @ Wt[N,K]^T + bias ----------
template<bool OUT_F32>
__global__ __launch_bounds__(256) void gemm_kern(
    const ushort* __restrict__ A, const ushort* __restrict__ Wt,
    const float* __restrict__ bias, void* __restrict__ out,
    int M, int N, int K)
{
  __shared__ char smem[16384];
  const int tid = threadIdx.x;
  const int lane = tid & 63, wave = tid >> 6;
  const int wm = wave >> 1, wn = wave & 1;
  const int nt = N >> 7;
  const int bm = blockIdx.x / nt, bn = blockIdx.x % nt;
  const long m0 = (long)bm * 128, n0 = (long)bn * 128;

  f32x4 acc[4][4] = {};
  const int KT = K >> 5;
  for (int kt = 0; kt < KT; ++kt) {
    #pragma unroll
    for (int i = 0; i < 4; ++i) {
      const int c = wave * 4 + i;
      const int isB = c >> 3;
      const int cc = c & 7;
      const int kgrp = cc >> 1, rhalf = cc & 1;
      const int row = rhalf * 64 + lane;
      const ushort* src = (isB ? Wt + (n0 + row) * (long)K : A + (m0 + row) * (long)K)
                          + (long)kt * 32 + kgrp * 8;
      gll16(src, smem + isB * 8192 + kgrp * 2048 + rhalf * 1024);
    }
    __syncthreads();
    const char* Ab = smem + (lane >> 4) * 2048;
    const char* Bb = smem + 8192 + (lane >> 4) * 2048;
    short8 af[4], bf[4];
    #pragma unroll
    for (int i = 0; i < 4; ++i) {
      af[i] = *(const short8*)(Ab + (wm * 64 + i * 16 + (lane & 15)) * 16);
      bf[i] = *(const short8*)(Bb + (wn * 64 + i * 16 + (lane & 15)) * 16);
    }
    #pragma unroll
    for (int mi = 0; mi < 4; ++mi)
      #pragma unroll
      for (int ni = 0; ni < 4; ++ni)
        acc[mi][ni] = __builtin_amdgcn_mfma_f32_16x16x32_bf16(af[mi], bf[ni], acc[mi][ni], 0, 0, 0);
    __syncthreads();
  }
  #pragma unroll
  for (int ni = 0; ni < 4; ++ni) {
    const long n = n0 + wn * 64 + ni * 16 + (lane & 15);
    const float bv = bias[n];
    #pragma unroll
    for (int mi = 0; mi < 4; ++mi) {
      const long mrow = m0 + wm * 64 + mi * 16 + (lane >> 4) * 4;
      #pragma unroll
      for (int r = 0; r < 4; ++r) {
        const float v = acc[mi][ni][r] + bv;
        if (OUT_F32) ((float*)out)[(mrow + r) * (long)N + n] = v;
        else         ((ushort*)out)[(mrow + r) * (long)N + n] = bf16_rne(v);
      }
    }
  }
}

// ---------- recurrence: h_t = tanh(xu_t + W h_{t-1}) (args pre-scaled by SC) ----------
// EXACT round-2 structure (measured 2466us): 4 WGs x 16 batches, 512 threads =
// 8 waves (2/SIMD), 4 m-tiles/wave. W k-slices 0..11 pinned via asm, 12..15 in
// LDS (128KB). h ping-pong [2][16][512] bf16 (32KB), swz=(b&7)<<4 (r6 proved
// b<<4 is 27% WORSE despite 5x fewer counted conflicts - counter != LDS cost).
// 1 barrier/step; stores pre-barrier.
// ONLY delta vs r2: epilogue VALU trim (SC pre-folded -> no mul; upper-only
// clamp; v_cvt_pk_bf16_f32 packing). No LDS/scheduling changes.
__global__ __launch_bounds__(512, 2) void rec_kern(
    const ushort* __restrict__ XU,   // [B*S, H] bf16, SC-scaled; row = b*S + t
    const ushort* __restrict__ Wb,   // [H, H] bf16 row-major, SC-scaled
    ushort* __restrict__ Hst)        // [B*S, H] bf16 (unscaled h)
{
  extern __shared__ char smem[];     // [0,32K): h pingpong   [32K, 160K): W slices 12..15
  const int tid = threadIdx.x;
  const int lane = tid & 63;
  const int wave = tid >> 6;         // 0..7
  const int b = lane & 15;
  const int hi = lane >> 4;          // 0..3
  const int bg = blockIdx.x << 4;
  const int swz = (b & 7) << 4;      // r2 swizzle (empirically best)

  // stage W slices 12..15 -> LDS fragments [(s-12)][mtg][lane*16]
  #pragma unroll
  for (int i = 0; i < 16; ++i) {
    const int ch = wave * 16 + i;          // 0..127
    const int s = 12 + (ch >> 5);
    const int mt = ch & 31;
    const ushort* src = Wb + (size_t)(mt * 16 + b) * H_ + s * 32 + hi * 8;
    gll16(src, smem + 32768 + (size_t)(s - 12) * 32768 + mt * 1024);
  }
  // zero both h buffers (h_{-1} = 0 in buf 0)
  {
    f32x4 zz = 0.0f;
    *(f32x4*)(smem + tid * 64) = zz;
    *(f32x4*)(smem + tid * 64 + 16) = zz;
    *(f32x4*)(smem + tid * 64 + 32) = zz;
    *(f32x4*)(smem + tid * 64 + 48) = zz;
  }
  // W registers: slices 0..11 for this wave's 4 m-tiles, pinned live via asm
  short8 wreg[4][12];
  #pragma unroll
  for (int mt = 0; mt < 4; ++mt) {
    const int mtg = wave * 4 + mt;
    const ushort* wrow = Wb + (size_t)(mtg * 16 + b) * H_ + hi * 8;
    #pragma unroll
    for (int s = 0; s < 12; ++s)
      wreg[mt][s] = *(const short8*)(wrow + s * 32);
  }
  #pragma unroll
  for (int mt = 0; mt < 4; ++mt)
    #pragma unroll
    for (int s = 0; s < 12; ++s)
      asm volatile("" : "+v"(wreg[mt][s]));
  __syncthreads();

  const ushort* xup = XU + (size_t)(bg + b) * S_ * H_ + wave * 64 + hi * 4;
  ushort* hgp = Hst + (size_t)(bg + b) * S_ * H_ + wave * 64 + hi * 4;
  const int hoff = b * 1024;                     // within h buffer
  const int woff = (wave * 128 + hi * 8);        // epilogue LDS write base (bytes, pre-XOR)

  for (int t = 0; t < S_; ++t) {
    // issue xu loads now; consumed in the epilogue (~2k cycles later)
    uint2 xu[4];
    #pragma unroll
    for (int mt = 0; mt < 4; ++mt)
      xu[mt] = *(const uint2*)(xup + mt * 16);
    xup += H_;

    const char* hb = smem + (t & 1) * 16384 + hoff;    // h_{t-1}
    f32x4 acc[4] = {};
    #pragma unroll
    for (int s = 0; s < 16; ++s) {
      const short8 bfrag = *(const short8*)(hb + ((s * 64 + hi * 16) ^ swz));
      #pragma unroll
      for (int mt = 0; mt < 4; ++mt) {
        short8 w;
        if (s < 12) w = wreg[mt][s];
        else w = *(const short8*)(smem + 32768 + (s - 12) * 32768 + (wave * 4 + mt) * 1024 + lane * 16);
        acc[mt] = __builtin_amdgcn_mfma_f32_16x16x32_bf16(w, bfrag, acc[mt], 0, 0, 0);
      }
    }
    // epilogue (trimmed): h_t = tanh_pre(acc + xu), cvt_pk pack, LDS + global store
    char* hw = smem + ((t + 1) & 1) * 16384 + hoff;
    #pragma unroll
    for (int mt = 0; mt < 4; ++mt) {
      const float h0 = tanh_pre(acc[mt][0] + bf16_f((ushort)(xu[mt].x & 0xFFFFu)));
      const float h1 = tanh_pre(acc[mt][1] + bf16_f((ushort)(xu[mt].x >> 16)));
      const float h2 = tanh_pre(acc[mt][2] + bf16_f((ushort)(xu[mt].y & 0xFFFFu)));
      const float h3 = tanh_pre(acc[mt][3] + bf16_f((ushort)(xu[mt].y >> 16)));
      uint2 hv;
      hv.x = cvt_pk_bf16(h0, h1);
      hv.y = cvt_pk_bf16(h2, h3);
      *(uint2*)(hw + ((woff + mt * 32) ^ swz)) = hv;   // h for next step
      *(uint2*)(hgp + mt * 16) = hv;                   // h for head GEMM
    }
    hgp += H_;
    __syncthreads();  // h_t visible (and h_{t-1} reads done) before next step
  }
}

// ---------- launcher ----------
extern "C" void kernel_launch(void* const* d_in, const int* in_sizes, int n_in,
                              void* d_out, int out_size, void* d_ws, size_t ws_size,
                              hipStream_t stream) {
  const float* x     = (const float*)d_in[0];
  const float* U_w   = (const float*)d_in[1];
  const float* U_b   = (const float*)d_in[2];
  const float* W_w   = (const float*)d_in[3];
  const float* W_b   = (const float*)d_in[4];
  const float* V_w   = (const float*)d_in[5];
  const float* V_b   = (const float*)d_in[6];
  const float* fc1_w = (const float*)d_in[7];
  const float* fc1_b = (const float*)d_in[8];
  const float* fc2_w = (const float*)d_in[9];
  const float* fc2_b = (const float*)d_in[10];
  const float* fc3_w = (const float*)d_in[11];
  const float* fc3_b = (const float*)d_in[12];

  char* ws = (char*)d_ws;
  // ws layout: [0,64M): Hst   [64M,96M): x_bf16   [128M, +~4M): weights/scratch
  ushort* Hst  = (ushort*)ws;                               // 67,108,864 B
  ushort* xb16 = (ushort*)(ws + 67108864);                  // 33,554,432 B
  char*   wb   = ws + 134217728;
  ushort* U_wb = (ushort*)wb;                    // 512*256  (SC-scaled)
  ushort* W_wb = U_wb + 131072;                  // 512*512  (SC-scaled)
  ushort* Wcb  = W_wb + 262144;                  // 256*512
  float*  C1   = (float*)(Wcb + 131072);         // 512*512 f32
  float*  C2   = C1 + 262144;                    // 512*512 f32
  float*  Wcf  = C2 + 262144;                    // 256*512 f32
  float*  cbias = Wcf + 131072;                  // 512 f32 (SC-scaled)
  float*  t1   = cbias + 512;                    // 512 f32
  float*  t2   = t1 + 512;                       // 512 f32
  float*  bc   = t2 + 512;                       // 256 f32
  ushort* bufA = (ushort*)d_out;                 // XU scratch (bf16), then fp32 out

  // bf16 staging converts (U_w, W_w, cbias pre-scaled by SC = 2*log2e)
  cvt_kern<<<2048, 256, 0, stream>>>(x, xb16, (long)M_ * I_, 1.0f);
  cvt_kern<<<128, 256, 0, stream>>>(U_w, U_wb, (long)H_ * I_, SC);
  cvt_kern<<<256, 256, 0, stream>>>(W_w, W_wb, (long)H_ * H_, SC);
  biascomb_kern<<<1, 512, 0, stream>>>(U_b, W_b, cbias);

  // fused head weights (fp32): C1 = fc1@V, C2 = fc2@C1, Wc = fc3@C2
  f32gemm_kern<<<dim3(32, 32), 256, 0, stream>>>(fc1_w, V_w, C1, H_, H_, H_);
  f32gemm_kern<<<dim3(32, 32), 256, 0, stream>>>(fc2_w, C1, C2, H_, H_, H_);
  f32gemm_kern<<<dim3(32, 16), 256, 0, stream>>>(fc3_w, C2, Wcf, O_, H_, H_);
  // bias chain: bc = fc3@(fc2@(fc1@V_b + b1) + b2) + b3  (wave-per-row matvecs)
  matvec_kern<<<128, 256, 0, stream>>>(fc1_w, V_b, fc1_b, t1, H_, H_);
  matvec_kern<<<128, 256, 0, stream>>>(fc2_w, t1, fc2_b, t2, H_, H_);
  matvec_kern<<<64, 256, 0, stream>>>(fc3_w, t2, fc3_b, bc, O_, H_);
  cvt_kern<<<128, 256, 0, stream>>>(Wcf, Wcb, (long)O_ * H_, 1.0f);

  // XU = x @ (SC*U^T) + SC*(U_b + W_b)   -> bufA (d_out as bf16 scratch)
  gemm_kern<false><<<dim3(512 * 4), 256, 0, stream>>>(xb16, U_wb, cbias, bufA, M_, H_, I_);

  // recurrence -> Hst
  hipFuncSetAttribute((const void*)rec_kern, hipFuncAttributeMaxDynamicSharedMemorySize, 163840);
  rec_kern<<<dim3(4), dim3(512), 163840, stream>>>(bufA, W_wb, Hst);

  // head: out = Hst @ Wc^T + bc -> d_out fp32 [B,S,O]
  gemm_kern<true><<<dim3(512 * 2), 256, 0, stream>>>(Hst, Wcb, bc, d_out, M_, O_, H_);

  (void)in_sizes; (void)n_in; (void)out_size; (void)ws_size;
}